// Round 7
// baseline (748.878 us; speedup 1.0000x reference)
//
#include <hip/hip_runtime.h>

#define N_DIS 25000
#define N_MIR 25000
#define NN    50000
#define E_NUM 600000
#define EMB   128

// bf16 <-> f32 via bit ops (no hip_bf16.h; no bf16 types in any kernel signature)
__device__ __forceinline__ float us2f(unsigned short u) {
    return __uint_as_float(((unsigned)u) << 16);
}
__device__ __forceinline__ unsigned short f2us(float f) {
    unsigned u = __float_as_uint(f);
    unsigned r = ((u >> 16) & 1u) + 0x7FFFu;  // round-to-nearest-even
    u += r;
    return (unsigned short)(u >> 16);
}
// Load element i of a float tensor stored as bf16 (isbf) or f32.
__device__ __forceinline__ float loadf(const void* p, size_t i, bool isbf) {
    if (isbf) return us2f(((const unsigned short*)p)[i]);
    return ((const float*)p)[i];
}

// ---------------- init: zero counts + flag ----------------
__global__ __launch_bounds__(256) void gs_zero(int* counts, int* flags) {
    int i = blockIdx.x * blockDim.x + threadIdx.x;
    if (i < NN) counts[i] = 0;
    if (i < 8) flags[i] = 0;
}

// set flag to a known value (host-determined dtype)
__global__ __launch_bounds__(64) void gs_setflag(int* flags, int v) {
    if (threadIdx.x == 0) flags[0] = v;
}

// dtype probe: bf16 data -> low-16 exponent near 127 (plausible w.p. ~0.99);
// f32 data -> low 16 bits are mantissa junk (plausible w.p. ~0.07). flags[0] += count.
__global__ __launch_bounds__(256) void gs_probe(const void* x, int* flags) {
    const unsigned* u = (const unsigned*)x;
    unsigned w = u[threadIdx.x];
    int e = (int)((w >> 7) & 0xFF);
    if (e >= 118 && e <= 135) atomicAdd(&flags[0], 1);
}

// ---------------- projection: out[row0+r, :] = x[r, :K] @ W[K,128] + b ----------------
__global__ __launch_bounds__(128) void gs_proj(const void* x, const void* W, const void* b,
                                               const int* flags, float* out, int row0, int K) {
    __shared__ float xs[4][512];
    const bool isbf = flags[0] > 128;
    const int t = threadIdx.x;
    const int r0 = blockIdx.x * 4;
    for (int r = 0; r < 4; ++r) {
        size_t base = (size_t)(r0 + r) * (size_t)K;
        for (int k = t; k < K; k += 128) xs[r][k] = loadf(x, base + k, isbf);
    }
    __syncthreads();
    float bb = loadf(b, t, isbf);  // biases are all-zero; reads 0.0 in both dtypes
    float a0 = bb, a1 = bb, a2 = bb, a3 = bb;
    for (int k = 0; k < K; ++k) {
        float w = loadf(W, (size_t)k * EMB + t, isbf);
        a0 += xs[0][k] * w;
        a1 += xs[1][k] * w;
        a2 += xs[2][k] * w;
        a3 += xs[3][k] * w;
    }
    float* op = out + (size_t)(row0 + r0) * EMB + t;
    op[0 * EMB] = a0;
    op[1 * EMB] = a1;
    op[2 * EMB] = a2;
    op[3 * EMB] = a3;
}

// ---------------- CSR build ----------------
__global__ __launch_bounds__(256) void gs_count(const int* dst, int* counts) {
    int e = blockIdx.x * blockDim.x + threadIdx.x;
    if (e < E_NUM) {
        unsigned d = (unsigned)dst[e];
        if (d < (unsigned)NN) atomicAdd(&counts[d], 1);
    }
}

__global__ __launch_bounds__(256) void gs_scan1(const int* counts, int* row_start, int* bsums) {
    __shared__ int tsum[256];
    const int t = threadIdx.x;
    const int base = blockIdx.x * 1024 + t * 4;
    int v0 = (base + 0 < NN) ? counts[base + 0] : 0;
    int v1 = (base + 1 < NN) ? counts[base + 1] : 0;
    int v2 = (base + 2 < NN) ? counts[base + 2] : 0;
    int v3 = (base + 3 < NN) ? counts[base + 3] : 0;
    int s = v0 + v1 + v2 + v3;
    tsum[t] = s;
    __syncthreads();
    for (int off = 1; off < 256; off <<= 1) {
        int xv = 0;
        if (t >= off) xv = tsum[t - off];
        __syncthreads();
        tsum[t] += xv;
        __syncthreads();
    }
    int excl = tsum[t] - s;
    if (base + 0 < NN) row_start[base + 0] = excl;
    excl += v0;
    if (base + 1 < NN) row_start[base + 1] = excl;
    excl += v1;
    if (base + 2 < NN) row_start[base + 2] = excl;
    excl += v2;
    if (base + 3 < NN) row_start[base + 3] = excl;
    if (t == 255) bsums[blockIdx.x] = tsum[255];
}

__global__ __launch_bounds__(64) void gs_scan2(int* bsums, int* row_start, int nb) {
    if (threadIdx.x == 0) {
        int run = 0;
        for (int i = 0; i < nb; ++i) {
            int v = bsums[i];
            bsums[i] = run;
            run += v;
        }
        row_start[NN] = run;
    }
}

__global__ __launch_bounds__(256) void gs_scan3(int* row_start, int* cursor, const int* bsums) {
    const int t = threadIdx.x;
    const int base = blockIdx.x * 1024 + t * 4;
    const int add = bsums[blockIdx.x];
    for (int i = 0; i < 4; ++i) {
        int idx = base + i;
        if (idx < NN) {
            int v = row_start[idx] + add;
            row_start[idx] = v;
            cursor[idx] = v;
        }
    }
}

__global__ __launch_bounds__(256) void gs_scatter(const int* src, const int* dst, int* cursor,
                                                  int* eidx) {
    int e = blockIdx.x * blockDim.x + threadIdx.x;
    if (e < E_NUM) {
        unsigned d = (unsigned)dst[e];
        unsigned sv = (unsigned)src[e];
        if (d < (unsigned)NN && sv < (unsigned)NN) {
            int p = atomicAdd(&cursor[d], 1);
            eidx[p] = (int)sv;
        }
    }
}

// ---------------- fused SAGE layer: out = [relu](x@Ws + mean_agg(x)@Wn + b) ----------------
// x: f32 [NN,128]. out: f32 (emit_bf16=0) or bf16-as-ushort (emit_bf16=1).
__global__ __launch_bounds__(128) void gs_sage(const float* x, const int* row_start,
                                               const int* eidx, const void* Ws, const void* Wn,
                                               const void* b, const int* flags, void* outp,
                                               int do_relu, int emit_bf16) {
    __shared__ float xs[4][EMB];
    __shared__ float as[4][EMB];
    const bool isbf = flags[0] > 128;
    const int t = threadIdx.x;
    const int r0 = blockIdx.x * 4;
    for (int r = 0; r < 4; ++r) {
        int n = r0 + r;
        int s0 = row_start[n];
        int s1 = row_start[n + 1];
        if (s0 < 0) s0 = 0;
        if (s1 > E_NUM) s1 = E_NUM;
        float acc = 0.f;
        for (int e = s0; e < s1; ++e) {
            unsigned s = (unsigned)eidx[e];
            if (s < (unsigned)NN) acc += x[(size_t)s * EMB + t];
        }
        as[r][t] = (s1 > s0) ? acc / (float)(s1 - s0) : 0.0f;
        xs[r][t] = x[(size_t)n * EMB + t];
    }
    __syncthreads();
    float bb = loadf(b, t, isbf);
    float a0 = bb, a1 = bb, a2 = bb, a3 = bb;
    for (int k = 0; k < EMB; ++k) {
        float ws = loadf(Ws, (size_t)k * EMB + t, isbf);
        float wn = loadf(Wn, (size_t)k * EMB + t, isbf);
        a0 += xs[0][k] * ws + as[0][k] * wn;
        a1 += xs[1][k] * ws + as[1][k] * wn;
        a2 += xs[2][k] * ws + as[2][k] * wn;
        a3 += xs[3][k] * ws + as[3][k] * wn;
    }
    if (do_relu) {
        a0 = a0 > 0.f ? a0 : 0.f;
        a1 = a1 > 0.f ? a1 : 0.f;
        a2 = a2 > 0.f ? a2 : 0.f;
        a3 = a3 > 0.f ? a3 : 0.f;
    }
    if (emit_bf16) {
        unsigned short* op = (unsigned short*)outp + (size_t)r0 * EMB + t;
        op[0 * EMB] = f2us(a0);
        op[1 * EMB] = f2us(a1);
        op[2 * EMB] = f2us(a2);
        op[3 * EMB] = f2us(a3);
    } else {
        float* op = (float*)outp + (size_t)r0 * EMB + t;
        op[0 * EMB] = a0;
        op[1 * EMB] = a1;
        op[2 * EMB] = a2;
        op[3 * EMB] = a3;
    }
}

extern "C" __attribute__((visibility("default"))) void kernel_launch(
    void* const* d_in, const int* in_sizes, int n_in, void* d_out, int out_size, void* d_ws,
    size_t ws_size, hipStream_t stream) {
    // ---- ordering + dtype from in_sizes[0] (d_features in dict order, W_d if sorted) ----
    // dict order: d_features -> 9,575,000 elements. sorted-key order: W_d -> 49,024 elements.
    int iDF = 0, iMF = 1, iSRC = 2, iDST = 3, iWD = 4, iBD = 5, iWM = 6, iBM = 7;
    int iWS1 = 8, iWN1 = 9, iB1 = 10, iWS2 = 11, iWN2 = 12, iB2 = 13;
    long u0 = in_sizes ? (long)in_sizes[0] : 9575000L;
    int dt = -1;  // -1 unknown (probe), 0 f32, 1 bf16
    if (u0 == 49024L || u0 == 98048L || u0 == 196096L) {
        iWD = 0; iWM = 1; iWN1 = 2; iWN2 = 3; iWS1 = 4; iWS2 = 5;
        iB1 = 6; iB2 = 7; iBD = 8; iBM = 9; iDF = 10; iDST = 11; iMF = 12; iSRC = 13;
        if (u0 == 98048L) dt = 1;
        else if (u0 == 196096L) dt = 0;
    } else {
        if (u0 == 19150000L) dt = 1;       // bytes, bf16
        else if (u0 == 38300000L) dt = 0;  // bytes, f32
        // 9,575,000 (elements): dtype unknown -> device probe
    }
    const void* d_features = d_in[iDF];
    const void* m_features = d_in[iMF];
    const int* src = (const int*)d_in[iSRC];
    const int* dst = (const int*)d_in[iDST];
    const void* W_d = d_in[iWD];
    const void* b_d = d_in[iBD];
    const void* W_m = d_in[iWM];
    const void* b_m = d_in[iBM];
    const void* W_self1 = d_in[iWS1];
    const void* W_neigh1 = d_in[iWN1];
    const void* b1 = d_in[iB1];
    const void* W_self2 = d_in[iWS2];
    const void* W_neigh2 = d_in[iWN2];
    const void* b2v = d_in[iB2];

    // ---- workspace layout (proven footprint, ~54.2 MB) ----
    char* w = (char*)d_ws;
    int* flags = (int*)(w + 0);            //        64 B
    int* counts = (int*)(w + 64);          //   200,000 B
    int* row_start = (int*)(w + 200064);   //   200,004 B (pad to 400128)
    int* cursor = (int*)(w + 400128);      //   200,000 B
    int* bsums = (int*)(w + 600128);       //       256 B
    int* eidx = (int*)(w + 600384);        // 2,400,000 B (pad to 3000448)
    float* hF = (float*)(w + 3000448);     // 25,600,000 B
    float* h1F = (float*)(w + 28600448);   // 25,600,000 B -> ends 54,200,448

    const int NB_SCAN = (NN + 1023) / 1024;  // 49
    const int EB = (E_NUM + 255) / 256;      // 2344
    const int ZB = (NN + 255) / 256;         // 196

    // init + dtype resolution (flags[0] > 128 => bf16)
    hipLaunchKernelGGL(gs_zero, dim3(ZB), dim3(256), 0, stream, counts, flags);
    if (dt == 1)
        hipLaunchKernelGGL(gs_setflag, dim3(1), dim3(64), 0, stream, flags, 1000);
    else if (dt == 0)
        hipLaunchKernelGGL(gs_setflag, dim3(1), dim3(64), 0, stream, flags, 0);
    else
        hipLaunchKernelGGL(gs_probe, dim3(1), dim3(256), 0, stream, d_features, flags);

    // CSR build (dims hardcoded)
    hipLaunchKernelGGL(gs_count, dim3(EB), dim3(256), 0, stream, dst, counts);
    hipLaunchKernelGGL(gs_scan1, dim3(NB_SCAN), dim3(256), 0, stream, counts, row_start, bsums);
    hipLaunchKernelGGL(gs_scan2, dim3(1), dim3(64), 0, stream, bsums, row_start, NB_SCAN);
    hipLaunchKernelGGL(gs_scan3, dim3(NB_SCAN), dim3(256), 0, stream, row_start, cursor, bsums);
    hipLaunchKernelGGL(gs_scatter, dim3(EB), dim3(256), 0, stream, src, dst, cursor, eidx);

    // per-type embedding projection -> hF (f32)
    hipLaunchKernelGGL(gs_proj, dim3(N_DIS / 4), dim3(128), 0, stream, d_features, W_d, b_d,
                       flags, hF, 0, 383);
    hipLaunchKernelGGL(gs_proj, dim3(N_MIR / 4), dim3(128), 0, stream, m_features, W_m, b_m,
                       flags, hF, N_DIS, 495);

    // layer 1 (relu, f32 out -> h1F)
    hipLaunchKernelGGL(gs_sage, dim3(NN / 4), dim3(128), 0, stream, hF, row_start, eidx, W_self1,
                       W_neigh1, b1, flags, (void*)h1F, 1, 0);
    // layer 2 -> d_out as FLOAT32 (reference output dtype; the round-3..6 1.207 signature
    // was correct bf16 output packed into an f32-read buffer)
    hipLaunchKernelGGL(gs_sage, dim3(NN / 4), dim3(128), 0, stream, h1F, row_start, eidx,
                       W_self2, W_neigh2, b2v, flags, d_out, 0, 0);
}